// Round 2
// baseline (227.437 us; speedup 1.0000x reference)
//
#include <hip/hip_runtime.h>

// ASIC_87007447483060 — soft logic-rail update, fused single pass.
// Memory-bound: ~185 MB traffic -> ~29 us floor at 6.3 TB/s.

constexpr int N    = 1024;
constexpr int NP1  = N + 1;            // 1025
constexpr int PLANE = NP1 * NP1;       // 1050625

// Main kernel: one thread per interior pixel (r,c) in [0,n)^2.
// Computes outs[i][r][c] for all 4 planes, scattering to:
//   planes 0,1 -> (r, c);  planes 2,3 -> (r+1, c+1)
// Inputs gathered from pristine rail_state (+ x override on plane 3 col 0).
__global__ __launch_bounds__(256) void asic_main(
    const float* __restrict__ x,
    const float* __restrict__ tg,
    const float* __restrict__ rail,
    const int*  __restrict__ mask,
    float* __restrict__ out)
{
    const int tid = blockIdx.x * 256 + threadIdx.x;
    const int r = tid >> 10;         // /N
    const int c = tid & (N - 1);     // %N
    const float g0 = tg[0];

    // new_inputs gathers (each rail element read once per thread, reused 4x)
    float u[4];
    u[0] = rail[0 * PLANE + (r + 1) * NP1 + (c + 1)];
    u[1] = rail[1 * PLANE + (r + 1) * NP1 + (c + 1)];
    u[2] = rail[2 * PLANE + r * NP1 + c];
    u[3] = (c == 0) ? x[r] : rail[3 * PLANE + r * NP1 + c];

    // F0[j] = 1-|0-u_j|, F1[j] = 1-|1-u_j|  (soft-AND factors)
    float F0[4], F1[4];
#pragma unroll
    for (int j = 0; j < 4; ++j) {
        F0[j] = 1.0f - fabsf(u[j]);
        F1[j] = 1.0f - fabsf(1.0f - u[j]);
    }

    const int pix = r * N + c;

#pragma unroll
    for (int i = 0; i < 4; ++i) {
        // others[i] = ascending j != i
        const int o0 = (i == 0) ? 1 : 0;
        const int o1 = (i <= 1) ? 2 : 1;
        const int o2 = (i <= 2) ? 3 : 2;

        // w[p] = F_{p>>2}[o0] * F_{(p>>1)&1}[o1] * F_{p&1}[o2]
        const float h00 = F0[o1] * F0[o2];
        const float h01 = F0[o1] * F1[o2];
        const float h10 = F1[o1] * F0[o2];
        const float h11 = F1[o1] * F1[o2];
        float w[8];
        w[0] = F0[o0] * h00; w[1] = F0[o0] * h01;
        w[2] = F0[o0] * h10; w[3] = F0[o0] * h11;
        w[4] = F1[o0] * h00; w[5] = F1[o0] * h01;
        w[6] = F1[o0] * h10; w[7] = F1[o0] * h11;

        // sum_p (tw_p*u + (1-tw_p)*(1-u)) * w_p
        //   = (2u-1) * sum tw_p w_p + (1-u) * sum w_p
        float s0 = 0.0f, s1 = 0.0f;
#pragma unroll
        for (int p = 0; p < 8; ++p) {
            const float t = tg[(i * 8 + p) * (N * N) + pix];  // read exactly once
            const float tw = __builtin_amdgcn_rcpf(1.0f + __expf(-t));  // sigmoid
            s0 += w[p];
            s1 = fmaf(tw, w[p], s1);
        }
        const float A = 2.0f * u[i] - 1.0f;
        const float B = 1.0f - u[i];
        float acc = fmaf(A, s1, B * s0);
        acc = fminf(fmaxf(acc, 0.0f), 1.0f);   // clip to [0,1]

        const int flat = (i < 2) ? (i * PLANE + r * NP1 + c)
                                 : (i * PLANE + (r + 1) * NP1 + (c + 1));
        out[flat] = acc * (float)mask[flat] * g0;
    }
}

// Boundary kernel: the 2n+1 passthrough cells per plane (8196 total).
// Planes 0,1: row n (all cols) + col n (rows 0..n-1) are NOT written by outs.
// Planes 2,3: row 0 (all cols) + col 0 (rows 1..n) are NOT written by outs.
// Plane 3 col 0 rows 0..n-1 carry x[r] (the view-write), row n keeps rail.
__global__ __launch_bounds__(256) void asic_boundary(
    const float* __restrict__ x,
    const float* __restrict__ tg,
    const float* __restrict__ rail,
    const int*  __restrict__ mask,
    float* __restrict__ out)
{
    const int per = 2 * N + 1;  // 2049 boundary cells per plane
    const int idx = blockIdx.x * 256 + threadIdx.x;
    if (idx >= 4 * per) return;
    const int plane = idx / per;
    const int k = idx % per;

    int r, c;
    if (plane < 2) {
        if (k <= N) { r = N; c = k; }          // bottom row
        else        { r = k - (N + 1); c = N; } // right col, rows 0..n-1
    } else {
        if (k <= N) { r = 0; c = k; }          // top row
        else        { r = k - N; c = 0; }       // left col, rows 1..n
    }

    const int flat = plane * PLANE + r * NP1 + c;
    float v;
    if (plane == 3 && c == 0 && r < N) v = x[r];
    else                               v = rail[flat];
    out[flat] = v * (float)mask[flat] * tg[0];
}

extern "C" void kernel_launch(void* const* d_in, const int* in_sizes, int n_in,
                              void* d_out, int out_size, void* d_ws, size_t ws_size,
                              hipStream_t stream) {
    const float* x    = (const float*)d_in[0];   // (n,)
    const float* tg   = (const float*)d_in[1];   // (4,8,n,n)
    const float* rail = (const float*)d_in[2];   // (4*(n+1)^2,)
    const int*   mask = (const int*)d_in[3];     // (4*(n+1)^2,)
    float* out = (float*)d_out;                  // (4*(n+1)^2,) f32

    asic_main<<<(N * N) / 256, 256, 0, stream>>>(x, tg, rail, mask, out);

    const int nb = 4 * (2 * N + 1);              // 8196
    asic_boundary<<<(nb + 255) / 256, 256, 0, stream>>>(x, tg, rail, mask, out);
}